// Round 1
// baseline (2923.343 us; speedup 1.0000x reference)
//
#include <hip/hip_runtime.h>

#define N_NODES 50000
#define N_EDGES 800000
#define IN_DIM 128
#define HIDDEN 128
#define OUT_DIM 40

// -------- SpMM via atomic scatter: out[dst] += w * x[src] (out pre-zeroed) ----
// 32 threads per edge; each thread handles 4 consecutive floats (float4 load).
__global__ __launch_bounds__(256) void spmm_atomic(
    const int* __restrict__ src, const int* __restrict__ dst,
    const float* __restrict__ w, const float* __restrict__ x,
    float* __restrict__ out)
{
    long long tid = (long long)blockIdx.x * blockDim.x + threadIdx.x;
    const long long total = (long long)N_EDGES * 32;
    if (tid >= total) return;
    int e = (int)(tid >> 5);
    int c = ((int)tid & 31) * 4;
    int s = src[e];
    int d = dst[e];
    float we = w[e];
    const float4 xv = *(const float4*)(x + (long long)s * IN_DIM + c);
    float* op = out + (long long)d * IN_DIM + c;
    atomicAdd(op + 0, we * xv.x);
    atomicAdd(op + 1, we * xv.y);
    atomicAdd(op + 2, we * xv.z);
    atomicAdd(op + 3, we * xv.w);
}

// -------- h1 = relu(h0 @ W1 + b1), one row per block, 128 threads ----------
__global__ __launch_bounds__(128) void lin1_relu(
    const float* __restrict__ h, const float* __restrict__ W1,
    const float* __restrict__ b1, float* __restrict__ out)
{
    __shared__ float xs[IN_DIM];
    int row = blockIdx.x;
    int col = threadIdx.x;
    xs[col] = h[(long long)row * IN_DIM + col];
    __syncthreads();
    float acc = b1[col];
    #pragma unroll 8
    for (int k = 0; k < IN_DIM; ++k)
        acc = fmaf(xs[k], W1[k * HIDDEN + col], acc);
    out[(long long)row * HIDDEN + col] = fmaxf(acc, 0.0f);
}

// -------- out = h2 @ W2 + b2, one row per block, 64 threads (40 active) ----
__global__ __launch_bounds__(64) void lin2(
    const float* __restrict__ h, const float* __restrict__ W2,
    const float* __restrict__ b2, float* __restrict__ out)
{
    __shared__ float xs[HIDDEN];
    int row = blockIdx.x;
    int t = threadIdx.x;
    xs[t]      = h[(long long)row * HIDDEN + t];
    xs[t + 64] = h[(long long)row * HIDDEN + t + 64];
    __syncthreads();
    if (t < OUT_DIM) {
        float acc = b2[t];
        #pragma unroll 8
        for (int k = 0; k < HIDDEN; ++k)
            acc = fmaf(xs[k], W2[k * OUT_DIM + t], acc);
        out[(long long)row * OUT_DIM + t] = acc;
    }
}

extern "C" void kernel_launch(void* const* d_in, const int* in_sizes, int n_in,
                              void* d_out, int out_size, void* d_ws, size_t ws_size,
                              hipStream_t stream)
{
    const float* x    = (const float*)d_in[0];
    const int*   esrc = (const int*)  d_in[1];
    const int*   edst = (const int*)  d_in[2];
    const float* ew   = (const float*)d_in[3];
    const float* W1   = (const float*)d_in[4];
    const float* b1   = (const float*)d_in[5];
    const float* W2   = (const float*)d_in[6];
    const float* b2   = (const float*)d_in[7];
    float* out = (float*)d_out;

    float* h0 = (float*)d_ws;                         // [N_NODES, 128]
    float* h1 = h0 + (size_t)N_NODES * HIDDEN;        // [N_NODES, 128]

    const size_t featBytes = sizeof(float) * (size_t)N_NODES * IN_DIM;
    const int spmmBlocks = (int)(((long long)N_EDGES * 32 + 255) / 256);

    // h0 = A @ x
    hipMemsetAsync(h0, 0, featBytes, stream);
    spmm_atomic<<<spmmBlocks, 256, 0, stream>>>(esrc, edst, ew, x, h0);

    // h1 = relu(h0 @ W1 + b1)
    lin1_relu<<<N_NODES, 128, 0, stream>>>(h0, W1, b1, h1);

    // h0 <- A @ h1   (reuse h0 buffer as h2)
    hipMemsetAsync(h0, 0, featBytes, stream);
    spmm_atomic<<<spmmBlocks, 256, 0, stream>>>(esrc, edst, ew, h1, h0);

    // out = h2 @ W2 + b2
    lin2<<<N_NODES, 64, 0, stream>>>(h0, W2, b2, out);
}

// Round 2
// 453.361 us; speedup vs baseline: 6.4482x; 6.4482x over previous
//
#include <hip/hip_runtime.h>

#define N_NODES 50000
#define N_EDGES 800000
#define IN_DIM 128
#define HIDDEN 128
#define OUT_DIM 40

struct __align__(8) Edge { int s; float w; };

// ---- 1) histogram of dst (int atomics on 200 KB, L2-resident, cheap) ------
__global__ __launch_bounds__(256) void hist_kernel(const int* __restrict__ dst,
                                                   int* __restrict__ cnt)
{
    int e = blockIdx.x * 256 + threadIdx.x;
    if (e < N_EDGES) atomicAdd(&cnt[dst[e]], 1);
}

// ---- 2) exclusive scan: cnt[50000] -> row_ptr[50001]; cnt becomes cursor --
__global__ __launch_bounds__(1024) void scan_kernel(int* __restrict__ cnt,
                                                    int* __restrict__ row_ptr)
{
    __shared__ int tmp[1024];
    const int t = threadIdx.x;
    const int CHUNK = (N_NODES + 1023) / 1024;   // 49
    int beg = t * CHUNK;
    int end = beg + CHUNK; if (end > N_NODES) end = N_NODES;
    int local = 0;
    for (int i = beg; i < end; ++i) local += cnt[i];
    tmp[t] = local;
    __syncthreads();
    for (int off = 1; off < 1024; off <<= 1) {   // Hillis-Steele inclusive
        int v = (t >= off) ? tmp[t - off] : 0;
        __syncthreads();
        tmp[t] += v;
        __syncthreads();
    }
    int running = tmp[t] - local;                // exclusive prefix
    for (int i = beg; i < end; ++i) {
        int c = cnt[i];
        row_ptr[i] = running;
        cnt[i] = running;                        // cursor copy for scatter
        running += c;
    }
    if (t == 0) row_ptr[N_NODES] = N_EDGES;
}

// ---- 3) scatter edges into dst-sorted order -------------------------------
__global__ __launch_bounds__(256) void scatter_kernel(const int* __restrict__ src,
                                                      const int* __restrict__ dst,
                                                      const float* __restrict__ w,
                                                      int* __restrict__ cursor,
                                                      Edge* __restrict__ edges)
{
    int e = blockIdx.x * 256 + threadIdx.x;
    if (e >= N_EDGES) return;
    int d = dst[e];
    int pos = atomicAdd(&cursor[d], 1);
    Edge ed; ed.s = src[e]; ed.w = w[e];
    edges[pos] = ed;
}

// ---- 4) gather SpMM: one wave per node, float2/lane, no atomics -----------
__global__ __launch_bounds__(256) void spmm_csr(const int* __restrict__ row_ptr,
                                                const Edge* __restrict__ edges,
                                                const float* __restrict__ x,
                                                float* __restrict__ out)
{
    int node = blockIdx.x * 4 + (threadIdx.x >> 6);
    int lane = threadIdx.x & 63;
    if (node >= N_NODES) return;
    int beg = row_ptr[node];
    int end = row_ptr[node + 1];
    const float2* xv = (const float2*)x;
    float2 acc = make_float2(0.f, 0.f);
    int j = beg;
    for (; j + 1 < end; j += 2) {
        Edge e0 = edges[j];
        Edge e1 = edges[j + 1];
        float2 a = xv[(long long)e0.s * 64 + lane];
        float2 b = xv[(long long)e1.s * 64 + lane];
        acc.x = fmaf(e0.w, a.x, acc.x);
        acc.y = fmaf(e0.w, a.y, acc.y);
        acc.x = fmaf(e1.w, b.x, acc.x);
        acc.y = fmaf(e1.w, b.y, acc.y);
    }
    if (j < end) {
        Edge e0 = edges[j];
        float2 a = xv[(long long)e0.s * 64 + lane];
        acc.x = fmaf(e0.w, a.x, acc.x);
        acc.y = fmaf(e0.w, a.y, acc.y);
    }
    ((float2*)out)[(long long)node * 64 + lane] = acc;
}

// ---- h1 = relu(h0 @ W1 + b1), 8 rows/block to amortize W1 traffic ---------
#define L1_ROWS 8
__global__ __launch_bounds__(128) void lin1_relu(const float* __restrict__ h,
                                                 const float* __restrict__ W1,
                                                 const float* __restrict__ b1,
                                                 float* __restrict__ out)
{
    __shared__ float xs[L1_ROWS][IN_DIM];
    int row0 = blockIdx.x * L1_ROWS;
    int col = threadIdx.x;
    #pragma unroll
    for (int r = 0; r < L1_ROWS; ++r)
        xs[r][col] = h[(long long)(row0 + r) * IN_DIM + col];
    __syncthreads();
    float acc[L1_ROWS];
    #pragma unroll
    for (int r = 0; r < L1_ROWS; ++r) acc[r] = b1[col];
    #pragma unroll 4
    for (int k = 0; k < IN_DIM; ++k) {
        float wv = W1[k * HIDDEN + col];
        #pragma unroll
        for (int r = 0; r < L1_ROWS; ++r)
            acc[r] = fmaf(xs[r][k], wv, acc[r]);
    }
    #pragma unroll
    for (int r = 0; r < L1_ROWS; ++r)
        out[(long long)(row0 + r) * HIDDEN + col] = fmaxf(acc[r], 0.f);
}

// ---- out = h2 @ W2 + b2, 8 rows/block -------------------------------------
#define L2_ROWS 8
__global__ __launch_bounds__(64) void lin2_kernel(const float* __restrict__ h,
                                                  const float* __restrict__ W2,
                                                  const float* __restrict__ b2,
                                                  float* __restrict__ out)
{
    __shared__ float xs[L2_ROWS][HIDDEN];
    int row0 = blockIdx.x * L2_ROWS;
    int t = threadIdx.x;
    #pragma unroll
    for (int r = 0; r < L2_ROWS; ++r) {
        xs[r][t]      = h[(long long)(row0 + r) * HIDDEN + t];
        xs[r][t + 64] = h[(long long)(row0 + r) * HIDDEN + t + 64];
    }
    __syncthreads();
    if (t >= OUT_DIM) return;
    float acc[L2_ROWS];
    #pragma unroll
    for (int r = 0; r < L2_ROWS; ++r) acc[r] = b2[t];
    #pragma unroll 4
    for (int k = 0; k < HIDDEN; ++k) {
        float wv = W2[k * OUT_DIM + t];
        #pragma unroll
        for (int r = 0; r < L2_ROWS; ++r)
            acc[r] = fmaf(xs[r][k], wv, acc[r]);
    }
    #pragma unroll
    for (int r = 0; r < L2_ROWS; ++r)
        out[(long long)(row0 + r) * OUT_DIM + t] = acc[r];
}

extern "C" void kernel_launch(void* const* d_in, const int* in_sizes, int n_in,
                              void* d_out, int out_size, void* d_ws, size_t ws_size,
                              hipStream_t stream)
{
    const float* x    = (const float*)d_in[0];
    const int*   esrc = (const int*)  d_in[1];
    const int*   edst = (const int*)  d_in[2];
    const float* ew   = (const float*)d_in[3];
    const float* W1   = (const float*)d_in[4];
    const float* b1   = (const float*)d_in[5];
    const float* W2   = (const float*)d_in[6];
    const float* b2   = (const float*)d_in[7];
    float* out = (float*)d_out;

    // workspace layout (58.0 MB total)
    float* h0      = (float*)d_ws;                         // 25.6 MB
    float* h1      = h0 + (size_t)N_NODES * HIDDEN;        // 25.6 MB
    int*   row_ptr = (int*)(h1 + (size_t)N_NODES * HIDDEN);// 200 KB (50001, padded)
    int*   cursor  = row_ptr + 50004;                      // 200 KB
    Edge*  edges   = (Edge*)(cursor + 50004);              // 6.4 MB

    const int eBlocks = (N_EDGES + 255) / 256;
    const int nWaveBlocks = (N_NODES + 3) / 4;

    // build CSR (once, reused by both SpMMs)
    hipMemsetAsync(cursor, 0, N_NODES * sizeof(int), stream);
    hist_kernel<<<eBlocks, 256, 0, stream>>>(edst, cursor);
    scan_kernel<<<1, 1024, 0, stream>>>(cursor, row_ptr);
    scatter_kernel<<<eBlocks, 256, 0, stream>>>(esrc, edst, ew, cursor, edges);

    // h0 = A @ x
    spmm_csr<<<nWaveBlocks, 256, 0, stream>>>(row_ptr, edges, x, h0);
    // h1 = relu(h0 @ W1 + b1)
    lin1_relu<<<N_NODES / L1_ROWS, 128, 0, stream>>>(h0, W1, b1, h1);
    // h0 <- A @ h1
    spmm_csr<<<nWaveBlocks, 256, 0, stream>>>(row_ptr, edges, h1, h0);
    // out = h2 @ W2 + b2
    lin2_kernel<<<N_NODES / L2_ROWS, 64, 0, stream>>>(h0, W2, b2, out);
}

// Round 3
// 347.560 us; speedup vs baseline: 8.4110x; 1.3044x over previous
//
#include <hip/hip_runtime.h>

#define N_NODES 50000
#define N_EDGES 800000
#define IN_DIM 128
#define HIDDEN 128
#define OUT_DIM 40

#define SCAN_BS 1024
#define SCAN_BLOCKS ((N_NODES + SCAN_BS - 1) / SCAN_BS)   // 49

struct __align__(8) Edge { int s; float w; };

// ---- 1) histogram of dst ---------------------------------------------------
__global__ __launch_bounds__(256) void hist_kernel(const int* __restrict__ dst,
                                                   int* __restrict__ cnt)
{
    int e = blockIdx.x * 256 + threadIdx.x;
    if (e < N_EDGES) atomicAdd(&cnt[dst[e]], 1);
}

// ---- 2a) per-block partial sums -------------------------------------------
__global__ __launch_bounds__(SCAN_BS) void scan_partial(const int* __restrict__ cnt,
                                                        int* __restrict__ block_sums)
{
    __shared__ int red[SCAN_BS / 64];
    int i = blockIdx.x * SCAN_BS + threadIdx.x;
    int v = (i < N_NODES) ? cnt[i] : 0;
    // wave reduce
    for (int off = 32; off > 0; off >>= 1) v += __shfl_down(v, off, 64);
    int wave = threadIdx.x >> 6, lane = threadIdx.x & 63;
    if (lane == 0) red[wave] = v;
    __syncthreads();
    if (threadIdx.x == 0) {
        int s = 0;
        #pragma unroll
        for (int wv = 0; wv < SCAN_BS / 64; ++wv) s += red[wv];
        block_sums[blockIdx.x] = s;
    }
}

// ---- 2b) scan the 49 block sums (one wave) --------------------------------
__global__ __launch_bounds__(64) void scan_sums(int* __restrict__ block_sums,
                                                int* __restrict__ row_ptr)
{
    int t = threadIdx.x;
    int v = (t < SCAN_BLOCKS) ? block_sums[t] : 0;
    int incl = v;
    for (int off = 1; off < 64; off <<= 1) {
        int u = __shfl_up(incl, off, 64);
        if (t >= off) incl += u;
    }
    if (t < SCAN_BLOCKS) block_sums[t] = incl - v;   // exclusive offsets
    if (t == 0) row_ptr[N_NODES] = N_EDGES;
}

// ---- 2c) block-local exclusive scan + offset; writes row_ptr & cursor -----
__global__ __launch_bounds__(SCAN_BS) void scan_final(const int* __restrict__ cnt,
                                                      const int* __restrict__ block_sums,
                                                      int* __restrict__ row_ptr,
                                                      int* __restrict__ cursor)
{
    __shared__ int tmp[SCAN_BS];
    int t = threadIdx.x;
    int i = blockIdx.x * SCAN_BS + t;
    int v = (i < N_NODES) ? cnt[i] : 0;
    tmp[t] = v;
    __syncthreads();
    for (int off = 1; off < SCAN_BS; off <<= 1) {    // Hillis-Steele inclusive
        int u = (t >= off) ? tmp[t - off] : 0;
        __syncthreads();
        tmp[t] += u;
        __syncthreads();
    }
    if (i < N_NODES) {
        int excl = tmp[t] - v + block_sums[blockIdx.x];
        row_ptr[i] = excl;
        cursor[i]  = excl;
    }
}

// ---- 3) scatter edges into dst-sorted order -------------------------------
__global__ __launch_bounds__(256) void scatter_kernel(const int* __restrict__ src,
                                                      const int* __restrict__ dst,
                                                      const float* __restrict__ w,
                                                      int* __restrict__ cursor,
                                                      Edge* __restrict__ edges)
{
    int e = blockIdx.x * 256 + threadIdx.x;
    if (e >= N_EDGES) return;
    int d = dst[e];
    int pos = atomicAdd(&cursor[d], 1);
    Edge ed; ed.s = src[e]; ed.w = w[e];
    edges[pos] = ed;
}

// ---- 4) gather SpMM: one wave per node, float2/lane, no atomics -----------
__global__ __launch_bounds__(256) void spmm_csr(const int* __restrict__ row_ptr,
                                                const Edge* __restrict__ edges,
                                                const float* __restrict__ x,
                                                float* __restrict__ out)
{
    int node = blockIdx.x * 4 + (threadIdx.x >> 6);
    int lane = threadIdx.x & 63;
    if (node >= N_NODES) return;
    int beg = row_ptr[node];
    int end = row_ptr[node + 1];
    const float2* xv = (const float2*)x;
    float2 acc = make_float2(0.f, 0.f);
    int j = beg;
    for (; j + 3 < end; j += 4) {
        Edge e0 = edges[j];
        Edge e1 = edges[j + 1];
        Edge e2 = edges[j + 2];
        Edge e3 = edges[j + 3];
        float2 a = xv[(long long)e0.s * 64 + lane];
        float2 b = xv[(long long)e1.s * 64 + lane];
        float2 c = xv[(long long)e2.s * 64 + lane];
        float2 d = xv[(long long)e3.s * 64 + lane];
        acc.x = fmaf(e0.w, a.x, acc.x);  acc.y = fmaf(e0.w, a.y, acc.y);
        acc.x = fmaf(e1.w, b.x, acc.x);  acc.y = fmaf(e1.w, b.y, acc.y);
        acc.x = fmaf(e2.w, c.x, acc.x);  acc.y = fmaf(e2.w, c.y, acc.y);
        acc.x = fmaf(e3.w, d.x, acc.x);  acc.y = fmaf(e3.w, d.y, acc.y);
    }
    for (; j < end; ++j) {
        Edge e0 = edges[j];
        float2 a = xv[(long long)e0.s * 64 + lane];
        acc.x = fmaf(e0.w, a.x, acc.x);  acc.y = fmaf(e0.w, a.y, acc.y);
    }
    ((float2*)out)[(long long)node * 64 + lane] = acc;
}

// ---- h1 = relu(h0 @ W1 + b1), 16 rows/block -------------------------------
#define L1_ROWS 16
__global__ __launch_bounds__(128) void lin1_relu(const float* __restrict__ h,
                                                 const float* __restrict__ W1,
                                                 const float* __restrict__ b1,
                                                 float* __restrict__ out)
{
    __shared__ float xs[L1_ROWS][IN_DIM];
    int row0 = blockIdx.x * L1_ROWS;
    int col = threadIdx.x;
    #pragma unroll
    for (int r = 0; r < L1_ROWS; ++r)
        xs[r][col] = h[(long long)(row0 + r) * IN_DIM + col];
    __syncthreads();
    float acc[L1_ROWS];
    #pragma unroll
    for (int r = 0; r < L1_ROWS; ++r) acc[r] = b1[col];
    #pragma unroll 4
    for (int k = 0; k < IN_DIM; ++k) {
        float wv = W1[k * HIDDEN + col];
        #pragma unroll
        for (int r = 0; r < L1_ROWS; ++r)
            acc[r] = fmaf(xs[r][k], wv, acc[r]);
    }
    #pragma unroll
    for (int r = 0; r < L1_ROWS; ++r)
        out[(long long)(row0 + r) * HIDDEN + col] = fmaxf(acc[r], 0.f);
}

// ---- out = h2 @ W2 + b2, 8 rows/block -------------------------------------
#define L2_ROWS 8
__global__ __launch_bounds__(64) void lin2_kernel(const float* __restrict__ h,
                                                  const float* __restrict__ W2,
                                                  const float* __restrict__ b2,
                                                  float* __restrict__ out)
{
    __shared__ float xs[L2_ROWS][HIDDEN];
    int row0 = blockIdx.x * L2_ROWS;
    int t = threadIdx.x;
    #pragma unroll
    for (int r = 0; r < L2_ROWS; ++r) {
        xs[r][t]      = h[(long long)(row0 + r) * HIDDEN + t];
        xs[r][t + 64] = h[(long long)(row0 + r) * HIDDEN + t + 64];
    }
    __syncthreads();
    if (t >= OUT_DIM) return;
    float acc[L2_ROWS];
    #pragma unroll
    for (int r = 0; r < L2_ROWS; ++r) acc[r] = b2[t];
    #pragma unroll 4
    for (int k = 0; k < HIDDEN; ++k) {
        float wv = W2[k * OUT_DIM + t];
        #pragma unroll
        for (int r = 0; r < L2_ROWS; ++r)
            acc[r] = fmaf(xs[r][k], wv, acc[r]);
    }
    #pragma unroll
    for (int r = 0; r < L2_ROWS; ++r)
        out[(long long)(row0 + r) * OUT_DIM + t] = acc[r];
}

extern "C" void kernel_launch(void* const* d_in, const int* in_sizes, int n_in,
                              void* d_out, int out_size, void* d_ws, size_t ws_size,
                              hipStream_t stream)
{
    const float* x    = (const float*)d_in[0];
    const int*   esrc = (const int*)  d_in[1];
    const int*   edst = (const int*)  d_in[2];
    const float* ew   = (const float*)d_in[3];
    const float* W1   = (const float*)d_in[4];
    const float* b1   = (const float*)d_in[5];
    const float* W2   = (const float*)d_in[6];
    const float* b2   = (const float*)d_in[7];
    float* out = (float*)d_out;

    // workspace layout
    float* h0         = (float*)d_ws;                          // 25.6 MB
    float* h1         = h0 + (size_t)N_NODES * HIDDEN;         // 25.6 MB
    int*   row_ptr    = (int*)(h1 + (size_t)N_NODES * HIDDEN); // 50001 ints (pad 50004)
    int*   cursor     = row_ptr + 50004;
    int*   block_sums = cursor + 50004;                        // 64 ints
    Edge*  edges      = (Edge*)(block_sums + 64);              // 6.4 MB

    const int eBlocks = (N_EDGES + 255) / 256;
    const int nWaveBlocks = (N_NODES + 3) / 4;

    // build CSR (reused by both SpMMs)
    hipMemsetAsync(cursor, 0, N_NODES * sizeof(int), stream);
    hist_kernel<<<eBlocks, 256, 0, stream>>>(edst, cursor);
    scan_partial<<<SCAN_BLOCKS, SCAN_BS, 0, stream>>>(cursor, block_sums);
    scan_sums<<<1, 64, 0, stream>>>(block_sums, row_ptr);
    scan_final<<<SCAN_BLOCKS, SCAN_BS, 0, stream>>>(cursor, block_sums, row_ptr, cursor);
    scatter_kernel<<<eBlocks, 256, 0, stream>>>(esrc, edst, ew, cursor, edges);

    // h0 = A @ x
    spmm_csr<<<nWaveBlocks, 256, 0, stream>>>(row_ptr, edges, x, h0);
    // h1 = relu(h0 @ W1 + b1)
    lin1_relu<<<N_NODES / L1_ROWS, 128, 0, stream>>>(h0, W1, b1, h1);
    // h0 <- A @ h1
    spmm_csr<<<nWaveBlocks, 256, 0, stream>>>(row_ptr, edges, h1, h0);
    // out = h2 @ W2 + b2
    lin2_kernel<<<N_NODES / L2_ROWS, 64, 0, stream>>>(h0, W2, b2, out);
}

// Round 4
// 310.050 us; speedup vs baseline: 9.4286x; 1.1210x over previous
//
#include <hip/hip_runtime.h>
#include <hip/hip_bf16.h>

#define N_NODES 50000
#define N_EDGES 800000
#define IN_DIM 128
#define HIDDEN 128
#define OUT_DIM 40

#define SCAN_BS 1024
#define SCAN_BLOCKS ((N_NODES + SCAN_BS - 1) / SCAN_BS)   // 49

struct __align__(8) Edge { int s; float w; };

// ---- 1) histogram of dst ---------------------------------------------------
__global__ __launch_bounds__(256) void hist_kernel(const int* __restrict__ dst,
                                                   int* __restrict__ cnt)
{
    int e = blockIdx.x * 256 + threadIdx.x;
    if (e < N_EDGES) atomicAdd(&cnt[dst[e]], 1);
}

// ---- 2a) per-block partial sums -------------------------------------------
__global__ __launch_bounds__(SCAN_BS) void scan_partial(const int* __restrict__ cnt,
                                                        int* __restrict__ block_sums)
{
    __shared__ int red[SCAN_BS / 64];
    int i = blockIdx.x * SCAN_BS + threadIdx.x;
    int v = (i < N_NODES) ? cnt[i] : 0;
    for (int off = 32; off > 0; off >>= 1) v += __shfl_down(v, off, 64);
    int wave = threadIdx.x >> 6, lane = threadIdx.x & 63;
    if (lane == 0) red[wave] = v;
    __syncthreads();
    if (threadIdx.x == 0) {
        int s = 0;
        #pragma unroll
        for (int wv = 0; wv < SCAN_BS / 64; ++wv) s += red[wv];
        block_sums[blockIdx.x] = s;
    }
}

// ---- 2b) scan the 49 block sums (one wave) --------------------------------
__global__ __launch_bounds__(64) void scan_sums(int* __restrict__ block_sums,
                                                int* __restrict__ row_ptr)
{
    int t = threadIdx.x;
    int v = (t < SCAN_BLOCKS) ? block_sums[t] : 0;
    int incl = v;
    for (int off = 1; off < 64; off <<= 1) {
        int u = __shfl_up(incl, off, 64);
        if (t >= off) incl += u;
    }
    if (t < SCAN_BLOCKS) block_sums[t] = incl - v;
    if (t == 0) row_ptr[N_NODES] = N_EDGES;
}

// ---- 2c) block-local exclusive scan + offset ------------------------------
__global__ __launch_bounds__(SCAN_BS) void scan_final(const int* __restrict__ cnt,
                                                      const int* __restrict__ block_sums,
                                                      int* __restrict__ row_ptr,
                                                      int* __restrict__ cursor)
{
    __shared__ int tmp[SCAN_BS];
    int t = threadIdx.x;
    int i = blockIdx.x * SCAN_BS + t;
    int v = (i < N_NODES) ? cnt[i] : 0;
    tmp[t] = v;
    __syncthreads();
    for (int off = 1; off < SCAN_BS; off <<= 1) {
        int u = (t >= off) ? tmp[t - off] : 0;
        __syncthreads();
        tmp[t] += u;
        __syncthreads();
    }
    if (i < N_NODES) {
        int excl = tmp[t] - v + block_sums[blockIdx.x];
        row_ptr[i] = excl;
        cursor[i]  = excl;
    }
}

// ---- 3) scatter edges into dst-sorted order -------------------------------
__global__ __launch_bounds__(256) void scatter_kernel(const int* __restrict__ src,
                                                      const int* __restrict__ dst,
                                                      const float* __restrict__ w,
                                                      int* __restrict__ cursor,
                                                      Edge* __restrict__ edges)
{
    int e = blockIdx.x * 256 + threadIdx.x;
    if (e >= N_EDGES) return;
    int d = dst[e];
    int pos = atomicAdd(&cursor[d], 1);
    Edge ed; ed.s = src[e]; ed.w = w[e];
    edges[pos] = ed;
}

// ---- gemm1: y = x @ W1 (fp32 in, bf16 out), 16 rows/block -----------------
#define G1_ROWS 16
__global__ __launch_bounds__(128) void gemm1_kernel(const float* __restrict__ x,
                                                    const float* __restrict__ W1,
                                                    __hip_bfloat16* __restrict__ y)
{
    __shared__ float xs[G1_ROWS][IN_DIM];
    int row0 = blockIdx.x * G1_ROWS;
    int col = threadIdx.x;
    #pragma unroll
    for (int r = 0; r < G1_ROWS; ++r)
        xs[r][col] = x[(long long)(row0 + r) * IN_DIM + col];
    __syncthreads();
    float acc[G1_ROWS];
    #pragma unroll
    for (int r = 0; r < G1_ROWS; ++r) acc[r] = 0.f;
    #pragma unroll 4
    for (int k = 0; k < IN_DIM; ++k) {
        float wv = W1[k * HIDDEN + col];
        #pragma unroll
        for (int r = 0; r < G1_ROWS; ++r)
            acc[r] = fmaf(xs[r][k], wv, acc[r]);
    }
    #pragma unroll
    for (int r = 0; r < G1_ROWS; ++r)
        y[(long long)(row0 + r) * HIDDEN + col] = __float2bfloat16(acc[r]);
}

// ---- spmm1: h1 = relu(A @ y + b1); wave/node, bf16x2 per lane -------------
__global__ __launch_bounds__(256) void spmm1_kernel(const int* __restrict__ row_ptr,
                                                    const Edge* __restrict__ edges,
                                                    const __hip_bfloat16* __restrict__ y,
                                                    const float* __restrict__ b1,
                                                    __hip_bfloat16* __restrict__ h1)
{
    int node = blockIdx.x * 4 + (threadIdx.x >> 6);
    int lane = threadIdx.x & 63;
    if (node >= N_NODES) return;
    int beg = row_ptr[node];
    int end = row_ptr[node + 1];
    const __hip_bfloat162* yv = (const __hip_bfloat162*)y;
    float ax = 0.f, ay = 0.f;
    int j = beg;
    for (; j + 3 < end; j += 4) {
        Edge e0 = edges[j];
        Edge e1 = edges[j + 1];
        Edge e2 = edges[j + 2];
        Edge e3 = edges[j + 3];
        __hip_bfloat162 v0 = yv[(long long)e0.s * 64 + lane];
        __hip_bfloat162 v1 = yv[(long long)e1.s * 64 + lane];
        __hip_bfloat162 v2 = yv[(long long)e2.s * 64 + lane];
        __hip_bfloat162 v3 = yv[(long long)e3.s * 64 + lane];
        ax = fmaf(e0.w, __low2float(v0), ax);  ay = fmaf(e0.w, __high2float(v0), ay);
        ax = fmaf(e1.w, __low2float(v1), ax);  ay = fmaf(e1.w, __high2float(v1), ay);
        ax = fmaf(e2.w, __low2float(v2), ax);  ay = fmaf(e2.w, __high2float(v2), ay);
        ax = fmaf(e3.w, __low2float(v3), ax);  ay = fmaf(e3.w, __high2float(v3), ay);
    }
    for (; j < end; ++j) {
        Edge e0 = edges[j];
        __hip_bfloat162 v0 = yv[(long long)e0.s * 64 + lane];
        ax = fmaf(e0.w, __low2float(v0), ax);
        ay = fmaf(e0.w, __high2float(v0), ay);
    }
    float2 bv = ((const float2*)b1)[lane];
    float rx = fmaxf(ax + bv.x, 0.f);
    float ry = fmaxf(ay + bv.y, 0.f);
    __hip_bfloat162 hv;
    hv.x = __float2bfloat16(rx);
    hv.y = __float2bfloat16(ry);
    ((__hip_bfloat162*)h1)[(long long)node * 64 + lane] = hv;
}

// ---- gemm2: g = h1 @ W2 (bf16 in, bf16 out), 8 rows/block -----------------
#define G2_ROWS 8
__global__ __launch_bounds__(64) void gemm2_kernel(const __hip_bfloat16* __restrict__ h1,
                                                   const float* __restrict__ W2,
                                                   __hip_bfloat16* __restrict__ g)
{
    __shared__ float xs[G2_ROWS][HIDDEN];
    int row0 = blockIdx.x * G2_ROWS;
    int t = threadIdx.x;
    #pragma unroll
    for (int r = 0; r < G2_ROWS; ++r) {
        xs[r][t]      = __bfloat162float(h1[(long long)(row0 + r) * HIDDEN + t]);
        xs[r][t + 64] = __bfloat162float(h1[(long long)(row0 + r) * HIDDEN + t + 64]);
    }
    __syncthreads();
    if (t >= OUT_DIM) return;
    float acc[G2_ROWS];
    #pragma unroll
    for (int r = 0; r < G2_ROWS; ++r) acc[r] = 0.f;
    #pragma unroll 4
    for (int k = 0; k < HIDDEN; ++k) {
        float wv = W2[k * OUT_DIM + t];
        #pragma unroll
        for (int r = 0; r < G2_ROWS; ++r)
            acc[r] = fmaf(xs[r][k], wv, acc[r]);
    }
    #pragma unroll
    for (int r = 0; r < G2_ROWS; ++r)
        g[(long long)(row0 + r) * OUT_DIM + t] = __float2bfloat16(acc[r]);
}

// ---- spmm2: out = A @ g + b2; wave/node, 40 active lanes ------------------
__global__ __launch_bounds__(256) void spmm2_kernel(const int* __restrict__ row_ptr,
                                                    const Edge* __restrict__ edges,
                                                    const __hip_bfloat16* __restrict__ g,
                                                    const float* __restrict__ b2,
                                                    float* __restrict__ out)
{
    int node = blockIdx.x * 4 + (threadIdx.x >> 6);
    int lane = threadIdx.x & 63;
    if (node >= N_NODES) return;
    if (lane >= OUT_DIM) return;
    int beg = row_ptr[node];
    int end = row_ptr[node + 1];
    float acc = 0.f;
    int j = beg;
    for (; j + 3 < end; j += 4) {
        Edge e0 = edges[j];
        Edge e1 = edges[j + 1];
        Edge e2 = edges[j + 2];
        Edge e3 = edges[j + 3];
        float v0 = __bfloat162float(g[(long long)e0.s * OUT_DIM + lane]);
        float v1 = __bfloat162float(g[(long long)e1.s * OUT_DIM + lane]);
        float v2 = __bfloat162float(g[(long long)e2.s * OUT_DIM + lane]);
        float v3 = __bfloat162float(g[(long long)e3.s * OUT_DIM + lane]);
        acc = fmaf(e0.w, v0, acc);
        acc = fmaf(e1.w, v1, acc);
        acc = fmaf(e2.w, v2, acc);
        acc = fmaf(e3.w, v3, acc);
    }
    for (; j < end; ++j) {
        Edge e0 = edges[j];
        acc = fmaf(e0.w, __bfloat162float(g[(long long)e0.s * OUT_DIM + lane]), acc);
    }
    out[(long long)node * OUT_DIM + lane] = acc + b2[lane];
}

extern "C" void kernel_launch(void* const* d_in, const int* in_sizes, int n_in,
                              void* d_out, int out_size, void* d_ws, size_t ws_size,
                              hipStream_t stream)
{
    const float* x    = (const float*)d_in[0];
    const int*   esrc = (const int*)  d_in[1];
    const int*   edst = (const int*)  d_in[2];
    const float* ew   = (const float*)d_in[3];
    const float* W1   = (const float*)d_in[4];
    const float* b1   = (const float*)d_in[5];
    const float* W2   = (const float*)d_in[6];
    const float* b2   = (const float*)d_in[7];
    float* out = (float*)d_out;

    // workspace layout
    __hip_bfloat16* y  = (__hip_bfloat16*)d_ws;                  // 12.8 MB
    __hip_bfloat16* h1 = y  + (size_t)N_NODES * HIDDEN;          // 12.8 MB
    __hip_bfloat16* g  = h1 + (size_t)N_NODES * HIDDEN;          // 4.0 MB
    int* row_ptr    = (int*)(g + (size_t)N_NODES * OUT_DIM);     // 50001 (pad 50004)
    int* cursor     = row_ptr + 50004;
    int* block_sums = cursor + 50004;                            // 64 ints
    Edge* edges     = (Edge*)(block_sums + 64);                  // 6.4 MB

    const int eBlocks = (N_EDGES + 255) / 256;
    const int nWaveBlocks = (N_NODES + 3) / 4;

    // build CSR (reused by both SpMMs)
    hipMemsetAsync(cursor, 0, N_NODES * sizeof(int), stream);
    hist_kernel<<<eBlocks, 256, 0, stream>>>(edst, cursor);
    scan_partial<<<SCAN_BLOCKS, SCAN_BS, 0, stream>>>(cursor, block_sums);
    scan_sums<<<1, 64, 0, stream>>>(block_sums, row_ptr);
    scan_final<<<SCAN_BLOCKS, SCAN_BS, 0, stream>>>(cursor, block_sums, row_ptr, cursor);
    scatter_kernel<<<eBlocks, 256, 0, stream>>>(esrc, edst, ew, cursor, edges);

    // y = x @ W1
    gemm1_kernel<<<N_NODES / G1_ROWS, 128, 0, stream>>>(x, W1, y);
    // h1 = relu(A @ y + b1)
    spmm1_kernel<<<nWaveBlocks, 256, 0, stream>>>(row_ptr, edges, y, b1, h1);
    // g = h1 @ W2
    gemm2_kernel<<<N_NODES / G2_ROWS, 64, 0, stream>>>(h1, W2, g);
    // out = A @ g + b2
    spmm2_kernel<<<nWaveBlocks, 256, 0, stream>>>(row_ptr, edges, g, b2, out);
}